// Round 1
// baseline (692.463 us; speedup 1.0000x reference)
//
#include <hip/hip_runtime.h>

// ---------------- problem constants ----------------
#define Bb 8
#define Tt 1024
#define Hh 8
#define DKk 64
#define NFf 512
#define DCc 256

typedef _Float16 v2h __attribute__((ext_vector_type(2)));
typedef _Float16 v4h __attribute__((ext_vector_type(4)));
typedef _Float16 v8h __attribute__((ext_vector_type(8)));
typedef float    v4f __attribute__((ext_vector_type(4)));

#define MFMA16(a,b,c) __builtin_amdgcn_mfma_f32_16x16x16f16((a),(b),(c),0,0,0)

__device__ inline void st8(_Float16* dst, v8h x){
    *(v4h*)dst     = __builtin_shufflevector(x,x,0,1,2,3);
    *(v4h*)(dst+4) = __builtin_shufflevector(x,x,4,5,6,7);
}

// ---------------- LayerNorm: x (8192,512) fp32 -> xn fp16 ----------------
__global__ __launch_bounds__(256) void k_ln(const float* __restrict__ x,
                                            const float* __restrict__ g,
                                            const float* __restrict__ be,
                                            _Float16* __restrict__ xn){
    int row = blockIdx.x; int tid = threadIdx.x;
    const float* xr = x + (size_t)row*512;
    float2 v = reinterpret_cast<const float2*>(xr)[tid];
    float s = v.x + v.y, sq = v.x*v.x + v.y*v.y;
    for (int off=32; off; off>>=1){ s += __shfl_down(s, off); sq += __shfl_down(sq, off); }
    __shared__ float ws_[4], wq_[4];
    __shared__ float mu_s, rs_s;
    int wid = tid>>6, lid = tid&63;
    if (lid==0){ ws_[wid]=s; wq_[wid]=sq; }
    __syncthreads();
    if (tid==0){
        float S=0,Q=0;
        for(int i=0;i<4;i++){S+=ws_[i];Q+=wq_[i];}
        float mu = S*(1.f/512.f);
        float var = Q*(1.f/512.f)-mu*mu;
        mu_s=mu; rs_s=rsqrtf(var+1e-5f);
    }
    __syncthreads();
    float mu=mu_s, rs=rs_s;
    float2 gv = reinterpret_cast<const float2*>(g)[tid];
    float2 bv = reinterpret_cast<const float2*>(be)[tid];
    v2h o; o[0] = (_Float16)((v.x-mu)*rs*gv.x + bv.x);
           o[1] = (_Float16)((v.y-mu)*rs*gv.y + bv.y);
    reinterpret_cast<v2h*>(xn + (size_t)row*512)[tid] = o;
}

// ---------------- Wcq = Wc(256,512) @ Wq(512,512), fp32 out ----------------
__global__ __launch_bounds__(512) void k_wcq(const float* __restrict__ Wc,
                                             const float* __restrict__ Wq,
                                             float* __restrict__ Wcq){
    __shared__ float wc[8][512];
    int i0 = blockIdx.x*8; int tid = threadIdx.x;
    for (int r=0;r<8;r++) wc[r][tid] = Wc[(size_t)(i0+r)*512 + tid];
    __syncthreads();
    float acc[8] = {0,0,0,0,0,0,0,0};
    for (int m=0;m<512;m++){
        float wq = Wq[(size_t)m*512+tid];
        #pragma unroll
        for (int r=0;r<8;r++) acc[r] += wc[r][m]*wq;
    }
    for (int r=0;r<8;r++) Wcq[(size_t)(i0+r)*512+tid] = acc[r];
}

// ---------------- bcq = bc @ Wq + bq ----------------
__global__ __launch_bounds__(512) void k_bcq(const float* __restrict__ bc,
                                             const float* __restrict__ Wq,
                                             const float* __restrict__ bq,
                                             float* __restrict__ bcq){
    int j = threadIdx.x;
    float a = bq[j];
    for (int m=0;m<512;m++) a += bc[m]*Wq[(size_t)m*512+j];
    bcq[j] = a;
}

// ---------------- generic GEMM: C(M,N) = A(M,K) @ W(K,N) + bias ----------------
// A: fp32 or fp16 ; W,bias: fp32 ; C: fp16 or fp32.  BM=64,BN=64,BK=32, 256 thr.
template<typename AT, typename CT>
__global__ __launch_bounds__(256) void k_gemm(const AT* __restrict__ A,
                                              const float* __restrict__ W,
                                              const float* __restrict__ bias,
                                              CT* __restrict__ C,
                                              int M, int N, int K){
    __shared__ _Float16 Al[64][36];
    __shared__ _Float16 Wt[64][36];
    int tid = threadIdx.x; int l = tid & 63; int w = tid >> 6;
    int l15 = l & 15, lq = l >> 4;
    int m0 = blockIdx.y*64, n0 = blockIdx.x*64;
    v4f acc[4] = {};
    float bv[4];
    #pragma unroll
    for (int nt=0;nt<4;nt++) bv[nt] = bias[n0 + nt*16 + l15];
    int arow = tid>>2, aseg = (tid&3)*8;
    int wk = tid>>3,  wn  = (tid&7)*8;
    for (int k0=0;k0<K;k0+=32){
        // stage A tile (64 x 32) as fp16
        if constexpr (sizeof(AT)==4){
            const float* src = (const float*)A + (size_t)(m0+arow)*K + k0 + aseg;
            float4 f0 = *(const float4*)src;
            float4 f1 = *(const float4*)(src+4);
            v4h h0; h0[0]=(_Float16)f0.x; h0[1]=(_Float16)f0.y; h0[2]=(_Float16)f0.z; h0[3]=(_Float16)f0.w;
            v4h h1; h1[0]=(_Float16)f1.x; h1[1]=(_Float16)f1.y; h1[2]=(_Float16)f1.z; h1[3]=(_Float16)f1.w;
            *(v4h*)&Al[arow][aseg]   = h0;
            *(v4h*)&Al[arow][aseg+4] = h1;
        } else {
            const _Float16* src = (const _Float16*)A + (size_t)(m0+arow)*K + k0 + aseg;
            v8h hv = *(const v8h*)src;
            st8(&Al[arow][aseg], hv);
        }
        // stage W tile (32 x 64) transposed -> Wt[n][k]
        {
            const float* src = W + (size_t)(k0+wk)*N + n0 + wn;
            float4 f0 = *(const float4*)src;
            float4 f1 = *(const float4*)(src+4);
            float tmp[8] = {f0.x,f0.y,f0.z,f0.w,f1.x,f1.y,f1.z,f1.w};
            #pragma unroll
            for (int j=0;j<8;j++) Wt[wn+j][wk] = (_Float16)tmp[j];
        }
        __syncthreads();
        #pragma unroll
        for (int kk=0; kk<32; kk+=16){
            v4h a = *(const v4h*)&Al[w*16 + l15][kk + lq*4];
            #pragma unroll
            for (int nt=0;nt<4;nt++){
                v4h b = *(const v4h*)&Wt[nt*16 + l15][kk + lq*4];
                acc[nt] = MFMA16(a, b, acc[nt]);
            }
        }
        __syncthreads();
    }
    #pragma unroll
    for (int nt=0;nt<4;nt++){
        #pragma unroll
        for (int i=0;i<4;i++){
            int row = m0 + w*16 + lq*4 + i;
            int col = n0 + nt*16 + l15;
            C[(size_t)row*N + col] = (CT)(acc[nt][i] + bv[nt]);
        }
    }
}

// ---------------- transpose q (b,t,c) -> qb (t, b*512+c) ----------------
__global__ __launch_bounds__(256) void k_qbT(const _Float16* __restrict__ q,
                                             _Float16* __restrict__ qb){
    int idx = blockIdx.x*256 + threadIdx.x;
    for (int o = idx; o < Bb*Tt*NFf; o += 4096*256){
        int c = o & 511;
        int b = (o >> 9) & 7;
        int t = o >> 12;
        qb[o] = q[((size_t)(b*Tt + t))*512 + c];
    }
}

// ---------------- scores: S[bh][t][s] = (q.k + q.posk)*scale, masked, fp16 ----
// grid (64 s-tiles, 64 t-tiles), 512 threads. LDS S-tile 64bh x 16t x 16s fp32.
__global__ __launch_bounds__(512) void k_scores(const _Float16* __restrict__ q,
                                                const _Float16* __restrict__ kbuf,
                                                const _Float16* __restrict__ qb,
                                                const float* __restrict__ posk,
                                                const int* __restrict__ mask,
                                                _Float16* __restrict__ Sg){
    __shared__ float S[64][16][16];
    __shared__ _Float16 QA[4][64][68];
    __shared__ _Float16 PK[4][16][68];
    int tid = threadIdx.x, l = tid&63, w = tid>>6;
    int l15 = l&15, lq = l>>4;
    int s0 = blockIdx.x*16, t0 = blockIdx.y*16;

    // ---- phase A: content scores per (b,h); wave w handles bh = w*8 + it
    for (int it=0; it<8; it++){
        int bh = w*8 + it; int b = bh>>3, h = bh&7;
        _Float16* Qa = &QA[w>>1][(w&1)*32][0];   // [16][68]
        _Float16* Kw = Qa + 16*68;               // [16][68]
        int r = l>>2, part = l&3;
        {
            const v8h* qs = (const v8h*)(q    + ((size_t)(b*Tt + t0 + r))*512 + h*64 + part*16);
            const v8h* ks = (const v8h*)(kbuf + ((size_t)(b*Tt + s0 + r))*512 + h*64 + part*16);
            v8h q0 = qs[0], q1 = qs[1];
            v8h k0 = ks[0], k1 = ks[1];
            st8(Qa + r*68 + part*16,     q0);
            st8(Qa + r*68 + part*16 + 8, q1);
            st8(Kw + r*68 + part*16,     k0);
            st8(Kw + r*68 + part*16 + 8, k1);
        }
        __syncthreads();
        v4f acc = {};
        #pragma unroll
        for (int ks=0; ks<4; ks++){
            v4h a  = *(const v4h*)(Qa + l15*68 + ks*16 + lq*4);
            v4h bf = *(const v4h*)(Kw + l15*68 + ks*16 + lq*4);
            acc = MFMA16(a, bf, acc);
        }
        #pragma unroll
        for (int i=0;i<4;i++) S[bh][lq*4+i][l15] = acc[i];
        __syncthreads();
    }

    // ---- phase B: position bias; pair p = w>>1 handles t-local {p*4+it}
    int p = w>>1, sub = w&1;
    int pl = sub*64 + l;          // 0..127 within pair
    for (int it=0; it<4; it++){
        int tl = p*4 + it;
        {   // stage Qb_t : all 64 bh x 64 d
            int row = pl>>1, part = pl&1;
            const v8h* src = (const v8h*)(qb + (size_t)(t0+tl)*4096 + row*64 + part*32);
            v8h d0=src[0], d1=src[1], d2=src[2], d3=src[3];
            _Float16* dst = &QA[p][row][part*32];
            st8(dst,    d0); st8(dst+8,  d1); st8(dst+16, d2); st8(dst+24, d3);
        }
        {   // stage pos_k[t0+tl][s0..s0+15][0..63] -> fp16
            int row = pl>>3, part = pl&7;
            const float4* src = (const float4*)(posk + ((size_t)((t0+tl)*Tt + s0 + row))*64 + part*8);
            float4 f0 = src[0], f1 = src[1];
            v4h h0; h0[0]=(_Float16)f0.x; h0[1]=(_Float16)f0.y; h0[2]=(_Float16)f0.z; h0[3]=(_Float16)f0.w;
            v4h h1; h1[0]=(_Float16)f1.x; h1[1]=(_Float16)f1.y; h1[2]=(_Float16)f1.z; h1[3]=(_Float16)f1.w;
            *(v4h*)&PK[p][row][part*8]   = h0;
            *(v4h*)&PK[p][row][part*8+4] = h1;
        }
        __syncthreads();
        #pragma unroll
        for (int mi=0; mi<2; mi++){
            int mt = sub*2 + mi;
            v4f acc = {};
            #pragma unroll
            for (int ks=0; ks<4; ks++){
                v4h a  = *(const v4h*)&QA[p][mt*16 + l15][ks*16 + lq*4];
                v4h bf = *(const v4h*)&PK[p][l15][ks*16 + lq*4];
                acc = MFMA16(a, bf, acc);
            }
            #pragma unroll
            for (int i=0;i<4;i++) S[mt*16 + lq*4 + i][tl][l15] += acc[i];
        }
        __syncthreads();
    }

    // ---- phase C: scale, mask, write fp16 (store in log2-domain scale)
    const float SC = 0.125f * 1.44269504088896f;
    int sl = tid & 15, grp = tid >> 4;   // 32 groups x 16 lanes
    for (int r=0; r<32; r++){
        int rowi = grp*32 + r;
        int bh = rowi>>4, tl = rowi&15;
        int b = bh>>3;
        float v = S[bh][tl][sl] * SC;
        int m = mask[((size_t)(b*Tt + t0+tl))*Tt + s0 + sl];
        if (m==0) v = -__builtin_inff();
        Sg[(size_t)bh*(Tt*Tt) + (size_t)(t0+tl)*Tt + s0+sl] = (_Float16)v;
    }
}

// ---------------- softmax + PV: per (bh, 64-row t-tile) -----------------
__global__ __launch_bounds__(512) void k_softpv(const _Float16* __restrict__ Sg,
                                                const _Float16* __restrict__ vbuf,
                                                _Float16* __restrict__ ao){
    int bh = blockIdx.y; int t0 = blockIdx.x*64;
    int b = bh>>3, h = bh&7;
    int tid=threadIdx.x, l=tid&63, w=tid>>6, l15=l&15, lq=l>>4;
    __shared__ float red[64][8];
    __shared__ float rowm[64], rowrcp[64];
    __shared__ _Float16 P[64][20];
    __shared__ _Float16 Vt[64][20];
    const _Float16* Srow = Sg + (size_t)bh*(Tt*Tt);

    int r1 = tid>>3, p1 = tid&7;
    {   // pass 1a: row max
        const v8h* src = (const v8h*)(Srow + (size_t)(t0+r1)*Tt + p1*128);
        float mx = -__builtin_inff();
        for (int j=0;j<16;j++){
            v8h x = src[j];
            #pragma unroll
            for (int e=0;e<8;e++) mx = fmaxf(mx, (float)x[e]);
        }
        red[r1][p1] = mx;
    }
    __syncthreads();
    if (tid<64){
        float m=-__builtin_inff();
        for (int j=0;j<8;j++) m = fmaxf(m, red[tid][j]);
        if (!(m > -1e37f)) m = 0.f;
        rowm[tid]=m;
    }
    __syncthreads();
    {   // pass 1b: row sum of 2^(x-m)
        float m = rowm[r1];
        const v8h* src = (const v8h*)(Srow + (size_t)(t0+r1)*Tt + p1*128);
        float s=0;
        for (int j=0;j<16;j++){
            v8h x = src[j];
            #pragma unroll
            for (int e=0;e<8;e++) s += exp2f((float)x[e] - m);
        }
        red[r1][p1] = s;
    }
    __syncthreads();
    if (tid<64){
        float s=0;
        for (int j=0;j<8;j++) s+=red[tid][j];
        rowrcp[tid] = (s>0.f) ? 1.f/s : 0.f;
    }
    __syncthreads();

    // pass 2: O = P @ V, staged per 16-s step
    int mt = w&3, nh = w>>2;
    v4f acc0 = {}, acc1 = {};
    for (int ss=0; ss<64; ss++){
        #pragma unroll
        for (int ph=0; ph<2; ph++){
            int row = (tid>>4) + ph*32; int slx = tid&15;
            float x = (float)Srow[(size_t)(t0+row)*Tt + ss*16 + slx];
            P[row][slx] = (_Float16)exp2f(x - rowm[row]);
        }
        #pragma unroll
        for (int ph=0; ph<2; ph++){
            int sr = (tid>>6) + ph*8; int d = tid&63;
            Vt[d][sr] = vbuf[((size_t)(b*Tt + ss*16 + sr))*512 + h*64 + d];
        }
        __syncthreads();
        v4h a  = *(const v4h*)&P[mt*16 + l15][lq*4];
        v4h b0 = *(const v4h*)&Vt[nh*32 + l15][lq*4];
        v4h b1 = *(const v4h*)&Vt[nh*32 + 16 + l15][lq*4];
        acc0 = MFMA16(a, b0, acc0);
        acc1 = MFMA16(a, b1, acc1);
        __syncthreads();
    }
    #pragma unroll
    for (int i=0;i<4;i++){
        int row = mt*16 + lq*4 + i;
        float rc = rowrcp[row];
        size_t base = ((size_t)(b*Tt + t0+row))*512 + h*64 + nh*32;
        ao[base + l15]      = (_Float16)(acc0[i]*rc);
        ao[base + 16 + l15] = (_Float16)(acc1[i]*rc);
    }
}

// ---------------- launch ----------------
extern "C" void kernel_launch(void* const* d_in, const int* in_sizes, int n_in,
                              void* d_out, int out_size, void* d_ws, size_t ws_size,
                              hipStream_t stream) {
    const float* x       = (const float*)d_in[0];
    const float* cond    = (const float*)d_in[1];
    const float* pos_k   = (const float*)d_in[2];
    const int*   mask    = (const int*)  d_in[3];
    const float* ln_g    = (const float*)d_in[4];
    const float* ln_b    = (const float*)d_in[5];
    const float* Wq      = (const float*)d_in[6];
    const float* bq      = (const float*)d_in[7];
    const float* Wk      = (const float*)d_in[8];
    const float* bk      = (const float*)d_in[9];
    const float* Wv      = (const float*)d_in[10];
    const float* bv      = (const float*)d_in[11];
    const float* Wo      = (const float*)d_in[12];
    const float* bo      = (const float*)d_in[13];
    const float* Wc      = (const float*)d_in[14];
    const float* bc      = (const float*)d_in[15];
    float* out = (float*)d_out;

    char* base = (char*)d_ws;
    const size_t OFF_S   = 0;                       // 134217728 B fp16 S
    const size_t OFF_XN  = 134217728;               // 8388608
    const size_t OFF_Q   = OFF_XN  + 8388608;
    const size_t OFF_QB  = OFF_Q   + 8388608;
    const size_t OFF_K   = OFF_QB  + 8388608;
    const size_t OFF_V   = OFF_K   + 8388608;
    const size_t OFF_AO  = OFF_V   + 8388608;
    const size_t OFF_WCQ = OFF_AO  + 8388608;
    const size_t OFF_BCQ = OFF_WCQ + 524288;

    _Float16* xn   = (_Float16*)(base + OFF_XN);
    _Float16* qbuf = (_Float16*)(base + OFF_Q);
    _Float16* qb   = (_Float16*)(base + OFF_QB);
    _Float16* kb   = (_Float16*)(base + OFF_K);
    _Float16* vb   = (_Float16*)(base + OFF_V);
    _Float16* ao   = (_Float16*)(base + OFF_AO);
    _Float16* Sg   = (_Float16*)(base + OFF_S);
    float*    wcq  = (float*)(base + OFF_WCQ);
    float*    bcq  = (float*)(base + OFF_BCQ);

    k_ln<<<dim3(Bb*Tt), dim3(256), 0, stream>>>(x, ln_g, ln_b, xn);
    k_wcq<<<dim3(32), dim3(512), 0, stream>>>(Wc, Wq, wcq);
    k_bcq<<<dim3(1), dim3(512), 0, stream>>>(bc, Wq, bq, bcq);

    k_gemm<float,_Float16><<<dim3(8,128), dim3(256), 0, stream>>>(cond, wcq, bcq, qbuf, Bb*Tt, 512, 256);
    k_gemm<_Float16,_Float16><<<dim3(8,128), dim3(256), 0, stream>>>(xn, Wk, bk, kb, Bb*Tt, 512, 512);
    k_gemm<_Float16,_Float16><<<dim3(8,128), dim3(256), 0, stream>>>(xn, Wv, bv, vb, Bb*Tt, 512, 512);

    k_qbT<<<dim3(4096), dim3(256), 0, stream>>>(qbuf, qb);

    k_scores<<<dim3(64,64), dim3(512), 0, stream>>>(qbuf, kb, qb, pos_k, mask, Sg);
    k_softpv<<<dim3(16,64), dim3(512), 0, stream>>>(Sg, vb, ao);

    k_gemm<_Float16,float><<<dim3(8,128), dim3(256), 0, stream>>>(ao, Wo, bo, out, Bb*Tt, 512, 512);
}

// Round 2
// 661.987 us; speedup vs baseline: 1.0460x; 1.0460x over previous
//
#include <hip/hip_runtime.h>

// ---------------- problem constants ----------------
#define Bb 8
#define Tt 1024
#define Hh 8
#define DKk 64
#define NFf 512
#define DCc 256

typedef _Float16 v2h __attribute__((ext_vector_type(2)));
typedef _Float16 v4h __attribute__((ext_vector_type(4)));
typedef _Float16 v8h __attribute__((ext_vector_type(8)));
typedef float    v4f __attribute__((ext_vector_type(4)));

#define MFMA16(a,b,c) __builtin_amdgcn_mfma_f32_16x16x16f16((a),(b),(c),0,0,0)
#define MFMA32(a,b,c) __builtin_amdgcn_mfma_f32_16x16x32_f16((a),(b),(c),0,0,0)

__device__ inline void st8(_Float16* dst, v8h x){
    *(v4h*)dst     = __builtin_shufflevector(x,x,0,1,2,3);
    *(v4h*)(dst+4) = __builtin_shufflevector(x,x,4,5,6,7);
}

__device__ inline v8h cvt8(float4 a, float4 b){
    v8h r;
    r[0]=(_Float16)a.x; r[1]=(_Float16)a.y; r[2]=(_Float16)a.z; r[3]=(_Float16)a.w;
    r[4]=(_Float16)b.x; r[5]=(_Float16)b.y; r[6]=(_Float16)b.z; r[7]=(_Float16)b.w;
    return r;
}

// ---------------- LayerNorm: x (8192,512) fp32 -> xn fp16 ----------------
__global__ __launch_bounds__(256) void k_ln(const float* __restrict__ x,
                                            const float* __restrict__ g,
                                            const float* __restrict__ be,
                                            _Float16* __restrict__ xn){
    int row = blockIdx.x; int tid = threadIdx.x;
    const float* xr = x + (size_t)row*512;
    float2 v = reinterpret_cast<const float2*>(xr)[tid];
    float s = v.x + v.y, sq = v.x*v.x + v.y*v.y;
    for (int off=32; off; off>>=1){ s += __shfl_down(s, off); sq += __shfl_down(sq, off); }
    __shared__ float ws_[4], wq_[4];
    __shared__ float mu_s, rs_s;
    int wid = tid>>6, lid = tid&63;
    if (lid==0){ ws_[wid]=s; wq_[wid]=sq; }
    __syncthreads();
    if (tid==0){
        float S=0,Q=0;
        for(int i=0;i<4;i++){S+=ws_[i];Q+=wq_[i];}
        float mu = S*(1.f/512.f);
        float var = Q*(1.f/512.f)-mu*mu;
        mu_s=mu; rs_s=rsqrtf(var+1e-5f);
    }
    __syncthreads();
    float mu=mu_s, rs=rs_s;
    float2 gv = reinterpret_cast<const float2*>(g)[tid];
    float2 bv = reinterpret_cast<const float2*>(be)[tid];
    v2h o; o[0] = (_Float16)((v.x-mu)*rs*gv.x + bv.x);
           o[1] = (_Float16)((v.y-mu)*rs*gv.y + bv.y);
    reinterpret_cast<v2h*>(xn + (size_t)row*512)[tid] = o;
}

// ---------------- Wcq = Wc(256,512) @ Wq(512,512), fp32 out ----------------
__global__ __launch_bounds__(512) void k_wcq(const float* __restrict__ Wc,
                                             const float* __restrict__ Wq,
                                             float* __restrict__ Wcq){
    __shared__ float wc[8][512];
    int i0 = blockIdx.x*8; int tid = threadIdx.x;
    for (int r=0;r<8;r++) wc[r][tid] = Wc[(size_t)(i0+r)*512 + tid];
    __syncthreads();
    float acc[8] = {0,0,0,0,0,0,0,0};
    for (int m=0;m<512;m++){
        float wq = Wq[(size_t)m*512+tid];
        #pragma unroll
        for (int r=0;r<8;r++) acc[r] += wc[r][m]*wq;
    }
    for (int r=0;r<8;r++) Wcq[(size_t)(i0+r)*512+tid] = acc[r];
}

// ---------------- bcq = bc @ Wq + bq ----------------
__global__ __launch_bounds__(512) void k_bcq(const float* __restrict__ bc,
                                             const float* __restrict__ Wq,
                                             const float* __restrict__ bq,
                                             float* __restrict__ bcq){
    int j = threadIdx.x;
    float a = bq[j];
    for (int m=0;m<512;m++) a += bc[m]*Wq[(size_t)m*512+j];
    bcq[j] = a;
}

// ---------------- generic GEMM: C(M,N) = A(M,K) @ W(K,N) + bias ----------------
template<typename AT, typename CT>
__global__ __launch_bounds__(256) void k_gemm(const AT* __restrict__ A,
                                              const float* __restrict__ W,
                                              const float* __restrict__ bias,
                                              CT* __restrict__ C,
                                              int M, int N, int K){
    __shared__ _Float16 Al[64][36];
    __shared__ _Float16 Wt[64][36];
    int tid = threadIdx.x; int l = tid & 63; int w = tid >> 6;
    int l15 = l & 15, lq = l >> 4;
    int m0 = blockIdx.y*64, n0 = blockIdx.x*64;
    v4f acc[4] = {};
    float bv[4];
    #pragma unroll
    for (int nt=0;nt<4;nt++) bv[nt] = bias[n0 + nt*16 + l15];
    int arow = tid>>2, aseg = (tid&3)*8;
    int wk = tid>>3,  wn  = (tid&7)*8;
    for (int k0=0;k0<K;k0+=32){
        if constexpr (sizeof(AT)==4){
            const float* src = (const float*)A + (size_t)(m0+arow)*K + k0 + aseg;
            float4 f0 = *(const float4*)src;
            float4 f1 = *(const float4*)(src+4);
            v4h h0; h0[0]=(_Float16)f0.x; h0[1]=(_Float16)f0.y; h0[2]=(_Float16)f0.z; h0[3]=(_Float16)f0.w;
            v4h h1; h1[0]=(_Float16)f1.x; h1[1]=(_Float16)f1.y; h1[2]=(_Float16)f1.z; h1[3]=(_Float16)f1.w;
            *(v4h*)&Al[arow][aseg]   = h0;
            *(v4h*)&Al[arow][aseg+4] = h1;
        } else {
            const _Float16* src = (const _Float16*)A + (size_t)(m0+arow)*K + k0 + aseg;
            v8h hv = *(const v8h*)src;
            st8(&Al[arow][aseg], hv);
        }
        {
            const float* src = W + (size_t)(k0+wk)*N + n0 + wn;
            float4 f0 = *(const float4*)src;
            float4 f1 = *(const float4*)(src+4);
            float tmp[8] = {f0.x,f0.y,f0.z,f0.w,f1.x,f1.y,f1.z,f1.w};
            #pragma unroll
            for (int j=0;j<8;j++) Wt[wn+j][wk] = (_Float16)tmp[j];
        }
        __syncthreads();
        #pragma unroll
        for (int kk=0; kk<32; kk+=16){
            v4h a = *(const v4h*)&Al[w*16 + l15][kk + lq*4];
            #pragma unroll
            for (int nt=0;nt<4;nt++){
                v4h b = *(const v4h*)&Wt[nt*16 + l15][kk + lq*4];
                acc[nt] = MFMA16(a, b, acc[nt]);
            }
        }
        __syncthreads();
    }
    #pragma unroll
    for (int nt=0;nt<4;nt++){
        #pragma unroll
        for (int i=0;i<4;i++){
            int row = m0 + w*16 + lq*4 + i;
            int col = n0 + nt*16 + l15;
            C[(size_t)row*N + col] = (CT)(acc[nt][i] + bv[nt]);
        }
    }
}

// ---------------- transpose q (b,t,c) -> qb (t, b*512+c) ----------------
__global__ __launch_bounds__(256) void k_qbT(const _Float16* __restrict__ q,
                                             _Float16* __restrict__ qb){
    int idx = blockIdx.x*256 + threadIdx.x;
    for (int o = idx; o < Bb*Tt*NFf; o += 4096*256){
        int c = o & 511;
        int b = (o >> 9) & 7;
        int t = o >> 12;
        qb[o] = q[((size_t)(b*Tt + t))*512 + c];
    }
}

// ---------------- scores v2: register MFMA frags direct from global ----------
// grid (64 s-tiles, 64 t-tiles), 256 threads (4 waves). LDS = S meeting tile.
__global__ __launch_bounds__(256) void k_scores(const _Float16* __restrict__ q,
                                                const _Float16* __restrict__ kbuf,
                                                const _Float16* __restrict__ qb,
                                                const float* __restrict__ posk,
                                                const int* __restrict__ mask,
                                                _Float16* __restrict__ Sg){
    __shared__ float S[64][16][20];   // 80 KB, [bh][t][s] (pad 20)
    int tid = threadIdx.x, l = tid&63, w = tid>>6;
    int l15 = l&15, lq = l>>4;
    int s0 = blockIdx.x*16, t0 = blockIdx.y*16;

    // ---- phase A: content scores. wave w owns bh = w*16 .. w*16+15
    #pragma unroll 4
    for (int it=0; it<16; it++){
        int bh = w*16 + it; int b = bh>>3, h = bh&7;
        const _Float16* qp = q    + ((size_t)(b*Tt + t0 + l15))*NFf + h*DKk + lq*8;
        const _Float16* kp = kbuf + ((size_t)(b*Tt + s0 + l15))*NFf + h*DKk + lq*8;
        v8h a0 = *(const v8h*)qp;
        v8h a1 = *(const v8h*)(qp+32);
        v8h b0 = *(const v8h*)kp;
        v8h b1 = *(const v8h*)(kp+32);
        v4f acc = {};
        acc = MFMA32(a0,b0,acc);
        acc = MFMA32(a1,b1,acc);
        #pragma unroll
        for (int i=0;i<4;i++) S[bh][lq*4+i][l15] = acc[i];
    }
    __syncthreads();

    // ---- phase B: position bias. wave w owns tl = w*4 .. w*4+3
    for (int it=0; it<4; it++){
        int tl = w*4 + it; int t = t0 + tl;
        const float* pk = posk + ((size_t)t*Tt + s0 + l15)*DKk + lq*8;
        float4 f0 = *(const float4*)pk;
        float4 f1 = *(const float4*)(pk+4);
        float4 f2 = *(const float4*)(pk+32);
        float4 f3 = *(const float4*)(pk+36);
        v8h pb0 = cvt8(f0,f1);
        v8h pb1 = cvt8(f2,f3);
        const _Float16* qbp = qb + (size_t)t*4096 + l15*64 + lq*8;
        #pragma unroll
        for (int bt=0; bt<4; bt++){
            v8h qa0 = *(const v8h*)(qbp + bt*1024);
            v8h qa1 = *(const v8h*)(qbp + bt*1024 + 32);
            v4f acc = {};
            acc = MFMA32(qa0,pb0,acc);
            acc = MFMA32(qa1,pb1,acc);
            #pragma unroll
            for (int i=0;i<4;i++) S[bt*16+lq*4+i][tl][l15] += acc[i];
        }
    }
    __syncthreads();

    // ---- phase C: scale, mask, write fp16 (log2 domain)
    const float SC = 0.125f * 1.44269504088896f;
    const _Float16 NEGINF = (_Float16)(-__builtin_inff());
    #pragma unroll
    for (int rr=0; rr<4; rr++){
        int row = rr*256 + tid;
        int bh = row>>4, tl = row&15; int b = bh>>3;
        const float* sp = &S[bh][tl][0];
        const int*   mp = mask + ((size_t)(b*Tt + t0+tl))*Tt + s0;
        v8h o0, o1;
        #pragma unroll
        for (int j=0;j<8;j++){
            o0[j] = mp[j]   ? (_Float16)(sp[j]*SC)   : NEGINF;
        }
        #pragma unroll
        for (int j=0;j<8;j++){
            o1[j] = mp[8+j] ? (_Float16)(sp[8+j]*SC) : NEGINF;
        }
        _Float16* op = Sg + ((size_t)bh<<20) + (size_t)(t0+tl)*Tt + s0;
        *(v8h*)op     = o0;
        *(v8h*)(op+8) = o1;
    }
}

// ---------------- softpv v2: online stats (1 pass) + 64-wide PV steps --------
__global__ __launch_bounds__(512) void k_softpv(const _Float16* __restrict__ Sg,
                                                const _Float16* __restrict__ vbuf,
                                                _Float16* __restrict__ ao){
    int bh = blockIdx.y; int t0 = blockIdx.x*64;
    int b = bh>>3, h = bh&7;
    int tid = threadIdx.x, l = tid&63, w = tid>>6, l15 = l&15, lq = l>>4;
    __shared__ float red[64][8][2];
    __shared__ float rowm[64], rowrcp[64];
    __shared__ _Float16 P[2][64][72];
    __shared__ _Float16 Vl[2][64][72];
    const _Float16* Srow = Sg + ((size_t)bh<<20);

    // pass 1: per-row online (max, sumexp2) over all 1024 s
    int r1 = tid>>3, p1 = tid&7;
    {
        const v8h* src = (const v8h*)(Srow + (size_t)(t0+r1)*Tt + p1*128);
        float m = -3000.f, lsum = 0.f;
        for (int j=0;j<16;j++){
            v8h x = src[j];
            float x0=(float)x[0], x1=(float)x[1], x2=(float)x[2], x3=(float)x[3];
            float x4=(float)x[4], x5=(float)x[5], x6=(float)x[6], x7=(float)x[7];
            float mx = fmaxf(fmaxf(fmaxf(x0,x1),fmaxf(x2,x3)),
                             fmaxf(fmaxf(x4,x5),fmaxf(x6,x7)));
            float mn = fmaxf(m, mx);
            lsum *= exp2f(m - mn);
            m = mn;
            lsum += exp2f(x0-mn)+exp2f(x1-mn)+exp2f(x2-mn)+exp2f(x3-mn)
                  + exp2f(x4-mn)+exp2f(x5-mn)+exp2f(x6-mn)+exp2f(x7-mn);
        }
        red[r1][p1][0] = m; red[r1][p1][1] = lsum;
    }
    __syncthreads();
    if (tid < 64){
        float M = -3000.f, L = 0.f;
        #pragma unroll
        for (int p=0;p<8;p++) M = fmaxf(M, red[tid][p][0]);
        #pragma unroll
        for (int p=0;p<8;p++) L += red[tid][p][1]*exp2f(red[tid][p][0]-M);
        rowm[tid] = M;
        rowrcp[tid] = (L>0.f) ? 1.f/L : 0.f;
    }
    __syncthreads();

    // pass 2: O = P @ V over 16 s-steps of 64, double-buffered staging
    int ttile = w&3, dp = w>>2;
    int d0 = dp*2, d1 = dp*2+1;
    v4f oa = {}, ob = {};
    int pr = tid>>3, seg = tid&7;
    for (int ss=0; ss<16; ss++){
        int cur = ss&1;
        v8h x = *(const v8h*)(Srow + (size_t)(t0+pr)*Tt + ss*64 + seg*8);
        float mr = rowm[pr];
        v8h pv;
        #pragma unroll
        for (int e=0;e<8;e++) pv[e] = (_Float16)exp2f((float)x[e] - mr);
        *(v8h*)&P[cur][pr][seg*8] = pv;
        v8h vv = *(const v8h*)(vbuf + ((size_t)(b*Tt + ss*64 + pr))*NFf + h*DKk + seg*8);
        *(v8h*)&Vl[cur][pr][seg*8] = vv;
        __syncthreads();
        #pragma unroll
        for (int kk=0; kk<4; kk++){
            v4h a = *(const v4h*)&P[cur][ttile*16 + l15][kk*16 + lq*4];
            v4h b0v, b1v;
            #pragma unroll
            for (int j=0;j<4;j++){
                b0v[j] = Vl[cur][kk*16+lq*4+j][d0*16+l15];
                b1v[j] = Vl[cur][kk*16+lq*4+j][d1*16+l15];
            }
            oa = MFMA16(a, b0v, oa);
            ob = MFMA16(a, b1v, ob);
        }
        // no trailing barrier: double buffer makes it safe
    }
    #pragma unroll
    for (int i=0;i<4;i++){
        int trow = ttile*16 + lq*4 + i;
        float rc = rowrcp[trow];
        size_t base = ((size_t)(b*Tt + t0 + trow))*NFf + h*DKk;
        ao[base + d0*16 + l15] = (_Float16)(oa[i]*rc);
        ao[base + d1*16 + l15] = (_Float16)(ob[i]*rc);
    }
}

// ---------------- launch ----------------
extern "C" void kernel_launch(void* const* d_in, const int* in_sizes, int n_in,
                              void* d_out, int out_size, void* d_ws, size_t ws_size,
                              hipStream_t stream) {
    const float* x       = (const float*)d_in[0];
    const float* cond    = (const float*)d_in[1];
    const float* pos_k   = (const float*)d_in[2];
    const int*   mask    = (const int*)  d_in[3];
    const float* ln_g    = (const float*)d_in[4];
    const float* ln_b    = (const float*)d_in[5];
    const float* Wq      = (const float*)d_in[6];
    const float* bq      = (const float*)d_in[7];
    const float* Wk      = (const float*)d_in[8];
    const float* bk      = (const float*)d_in[9];
    const float* Wv      = (const float*)d_in[10];
    const float* bv      = (const float*)d_in[11];
    const float* Wo      = (const float*)d_in[12];
    const float* bo      = (const float*)d_in[13];
    const float* Wc      = (const float*)d_in[14];
    const float* bc      = (const float*)d_in[15];
    float* out = (float*)d_out;

    char* base = (char*)d_ws;
    const size_t OFF_S   = 0;
    const size_t OFF_XN  = 134217728;
    const size_t OFF_Q   = OFF_XN  + 8388608;
    const size_t OFF_QB  = OFF_Q   + 8388608;
    const size_t OFF_K   = OFF_QB  + 8388608;
    const size_t OFF_V   = OFF_K   + 8388608;
    const size_t OFF_AO  = OFF_V   + 8388608;
    const size_t OFF_WCQ = OFF_AO  + 8388608;
    const size_t OFF_BCQ = OFF_WCQ + 524288;

    _Float16* xn   = (_Float16*)(base + OFF_XN);
    _Float16* qbuf = (_Float16*)(base + OFF_Q);
    _Float16* qb   = (_Float16*)(base + OFF_QB);
    _Float16* kb   = (_Float16*)(base + OFF_K);
    _Float16* vb   = (_Float16*)(base + OFF_V);
    _Float16* ao   = (_Float16*)(base + OFF_AO);
    _Float16* Sg   = (_Float16*)(base + OFF_S);
    float*    wcq  = (float*)(base + OFF_WCQ);
    float*    bcq  = (float*)(base + OFF_BCQ);

    k_ln<<<dim3(Bb*Tt), dim3(256), 0, stream>>>(x, ln_g, ln_b, xn);
    k_wcq<<<dim3(32), dim3(512), 0, stream>>>(Wc, Wq, wcq);
    k_bcq<<<dim3(1), dim3(512), 0, stream>>>(bc, Wq, bq, bcq);

    k_gemm<float,_Float16><<<dim3(8,128), dim3(256), 0, stream>>>(cond, wcq, bcq, qbuf, Bb*Tt, 512, 256);
    k_gemm<_Float16,_Float16><<<dim3(8,128), dim3(256), 0, stream>>>(xn, Wk, bk, kb, Bb*Tt, 512, 512);
    k_gemm<_Float16,_Float16><<<dim3(8,128), dim3(256), 0, stream>>>(xn, Wv, bv, vb, Bb*Tt, 512, 512);

    k_qbT<<<dim3(4096), dim3(256), 0, stream>>>(qbuf, qb);

    k_scores<<<dim3(64,64), dim3(256), 0, stream>>>(qbuf, kb, qb, pos_k, mask, Sg);
    k_softpv<<<dim3(16,64), dim3(512), 0, stream>>>(Sg, vb, ao);

    k_gemm<_Float16,float><<<dim3(8,128), dim3(256), 0, stream>>>(ao, Wo, bo, out, Bb*Tt, 512, 512);
}

// Round 4
// 449.939 us; speedup vs baseline: 1.5390x; 1.4713x over previous
//
#include <hip/hip_runtime.h>

// ---------------- problem constants ----------------
#define Bb 8
#define Tt 1024
#define Hh 8
#define DKk 64
#define NFf 512
#define DCc 256

typedef _Float16 v2h __attribute__((ext_vector_type(2)));
typedef _Float16 v4h __attribute__((ext_vector_type(4)));
typedef _Float16 v8h __attribute__((ext_vector_type(8)));
typedef float    v4f __attribute__((ext_vector_type(4)));

#define MFMA16(a,b,c) __builtin_amdgcn_mfma_f32_16x16x16f16((a),(b),(c),0,0,0)
#define MFMA32(a,b,c) __builtin_amdgcn_mfma_f32_16x16x32_f16((a),(b),(c),0,0,0)

// scale folded into q: 1/sqrt(64) * log2(e)  (scores live in log2 domain)
#define SCQ 0.1803368801111f

__device__ inline void st8(_Float16* dst, v8h x){
    *(v4h*)dst     = __builtin_shufflevector(x,x,0,1,2,3);
    *(v4h*)(dst+4) = __builtin_shufflevector(x,x,4,5,6,7);
}

__device__ inline v8h cvt8(float4 a, float4 b){
    v8h r;
    r[0]=(_Float16)a.x; r[1]=(_Float16)a.y; r[2]=(_Float16)a.z; r[3]=(_Float16)a.w;
    r[4]=(_Float16)b.x; r[5]=(_Float16)b.y; r[6]=(_Float16)b.z; r[7]=(_Float16)b.w;
    return r;
}

// XOR swizzle for [R][64] half LDS tiles; keeps 8-half granularity
__device__ inline int swz(int r, int c){ return (r*64 + c) ^ ((r&7)<<3); }

// ---------------- LayerNorm: x (8192,512) fp32 -> xn fp16 ----------------
__global__ __launch_bounds__(256) void k_ln(const float* __restrict__ x,
                                            const float* __restrict__ g,
                                            const float* __restrict__ be,
                                            _Float16* __restrict__ xn){
    int row = blockIdx.x; int tid = threadIdx.x;
    const float* xr = x + (size_t)row*512;
    float2 v = reinterpret_cast<const float2*>(xr)[tid];
    float s = v.x + v.y, sq = v.x*v.x + v.y*v.y;
    for (int off=32; off; off>>=1){ s += __shfl_down(s, off); sq += __shfl_down(sq, off); }
    __shared__ float ws_[4], wq_[4];
    __shared__ float mu_s, rs_s;
    int wid = tid>>6, lid = tid&63;
    if (lid==0){ ws_[wid]=s; wq_[wid]=sq; }
    __syncthreads();
    if (tid==0){
        float S=0,Q=0;
        for(int i=0;i<4;i++){S+=ws_[i];Q+=wq_[i];}
        float mu = S*(1.f/512.f);
        float var = Q*(1.f/512.f)-mu*mu;
        mu_s=mu; rs_s=rsqrtf(var+1e-5f);
    }
    __syncthreads();
    float mu=mu_s, rs=rs_s;
    float2 gv = reinterpret_cast<const float2*>(g)[tid];
    float2 bv = reinterpret_cast<const float2*>(be)[tid];
    v2h o; o[0] = (_Float16)((v.x-mu)*rs*gv.x + bv.x);
           o[1] = (_Float16)((v.y-mu)*rs*gv.y + bv.y);
    reinterpret_cast<v2h*>(xn + (size_t)row*512)[tid] = o;
}

// ---------------- Wcq = Wc(256,512) @ Wq(512,512), fp32 out ----------------
__global__ __launch_bounds__(512) void k_wcq(const float* __restrict__ Wc,
                                             const float* __restrict__ Wq,
                                             float* __restrict__ Wcq){
    __shared__ float wc[8][512];
    int i0 = blockIdx.x*8; int tid = threadIdx.x;
    for (int r=0;r<8;r++) wc[r][tid] = Wc[(size_t)(i0+r)*512 + tid];
    __syncthreads();
    float acc[8] = {0,0,0,0,0,0,0,0};
    for (int m=0;m<512;m++){
        float wq = Wq[(size_t)m*512+tid];
        #pragma unroll
        for (int r=0;r<8;r++) acc[r] += wc[r][m]*wq;
    }
    for (int r=0;r<8;r++) Wcq[(size_t)(i0+r)*512+tid] = acc[r];
}

// ---------------- bcq = bc @ Wq + bq ----------------
__global__ __launch_bounds__(512) void k_bcq(const float* __restrict__ bc,
                                             const float* __restrict__ Wq,
                                             const float* __restrict__ bq,
                                             float* __restrict__ bcq){
    int j = threadIdx.x;
    float a = bq[j];
    for (int m=0;m<512;m++) a += bc[m]*Wq[(size_t)m*512+j];
    bcq[j] = a;
}

// ---------------- generic GEMM: C(M,N) = (A(M,K) @ W(K,N) + bias)*scale -------
// QB: additionally write q-transposed layout qbT[t][b*512+c]
template<typename AT, typename CT, bool QB>
__global__ __launch_bounds__(256) void k_gemm(const AT* __restrict__ A,
                                              const float* __restrict__ W,
                                              const float* __restrict__ bias,
                                              CT* __restrict__ C,
                                              int M, int N, int K,
                                              float scale,
                                              _Float16* __restrict__ qbT){
    __shared__ _Float16 Al[64][36];
    __shared__ _Float16 Wt[64][36];
    int tid = threadIdx.x; int l = tid & 63; int w = tid >> 6;
    int l15 = l & 15, lq = l >> 4;
    int m0 = blockIdx.y*64, n0 = blockIdx.x*64;
    v4f acc[4] = {};
    float bv[4];
    #pragma unroll
    for (int nt=0;nt<4;nt++) bv[nt] = bias[n0 + nt*16 + l15];
    int arow = tid>>2, aseg = (tid&3)*8;
    int wk = tid>>3,  wn  = (tid&7)*8;
    for (int k0=0;k0<K;k0+=32){
        if constexpr (sizeof(AT)==4){
            const float* src = (const float*)A + (size_t)(m0+arow)*K + k0 + aseg;
            float4 f0 = *(const float4*)src;
            float4 f1 = *(const float4*)(src+4);
            *(v4h*)&Al[arow][aseg]   = (v4h){(_Float16)f0.x,(_Float16)f0.y,(_Float16)f0.z,(_Float16)f0.w};
            *(v4h*)&Al[arow][aseg+4] = (v4h){(_Float16)f1.x,(_Float16)f1.y,(_Float16)f1.z,(_Float16)f1.w};
        } else {
            const _Float16* src = (const _Float16*)A + (size_t)(m0+arow)*K + k0 + aseg;
            v8h hv = *(const v8h*)src;
            st8(&Al[arow][aseg], hv);
        }
        {
            const float* src = W + (size_t)(k0+wk)*N + n0 + wn;
            float4 f0 = *(const float4*)src;
            float4 f1 = *(const float4*)(src+4);
            float tmp[8] = {f0.x,f0.y,f0.z,f0.w,f1.x,f1.y,f1.z,f1.w};
            #pragma unroll
            for (int j=0;j<8;j++) Wt[wn+j][wk] = (_Float16)tmp[j];
        }
        __syncthreads();
        #pragma unroll
        for (int kk=0; kk<32; kk+=16){
            v4h a = *(const v4h*)&Al[w*16 + l15][kk + lq*4];
            #pragma unroll
            for (int nt=0;nt<4;nt++){
                v4h b = *(const v4h*)&Wt[nt*16 + l15][kk + lq*4];
                acc[nt] = MFMA16(a, b, acc[nt]);
            }
        }
        __syncthreads();
    }
    #pragma unroll
    for (int nt=0;nt<4;nt++){
        #pragma unroll
        for (int i=0;i<4;i++){
            int row = m0 + w*16 + lq*4 + i;
            int col = n0 + nt*16 + l15;
            float vfull = (acc[nt][i] + bv[nt])*scale;
            C[(size_t)row*N + col] = (CT)vfull;
            if constexpr (QB){
                int bI = row>>10, t = row&1023;
                qbT[((size_t)t<<12) + (bI<<9) + col] = (_Float16)vfull;
            }
        }
    }
}

// ---------------- bias: Sb[bh][t][s] = qs[bh,t,:]·posk[t,s,:], mask folded ----
// grid 1024 (one t per block), 256 thr; wave w owns s in [w*256, w*256+256)
__global__ __launch_bounds__(256) void k_bias(const _Float16* __restrict__ qb,
                                              const float* __restrict__ posk,
                                              const int* __restrict__ mask,
                                              _Float16* __restrict__ Sb){
    int t = blockIdx.x;
    int tid = threadIdx.x, l = tid&63, w = tid>>6, l15 = l&15, lq = l>>4;
    // resident B-frags: B[k=d][col=bh] = qb[t][bh*64+d]
    v8h bb[4][2];
    const _Float16* qbt = qb + ((size_t)t<<12);
    #pragma unroll
    for (int nt=0;nt<4;++nt){
        #pragma unroll
        for (int u=0;u<2;++u)
            bb[nt][u] = *(const v8h*)(qbt + (nt*16+l15)*64 + u*32 + lq*8);
    }
    const float* pkt = posk + ((size_t)t<<16);
    for (int st=0; st<16; ++st){
        int s0 = w*256 + st*16;
        const float* prow = pkt + (size_t)(s0 + l15)*64 + lq*8;
        float4 f0 = *(const float4*)(prow);
        float4 f1 = *(const float4*)(prow+4);
        float4 f2 = *(const float4*)(prow+32);
        float4 f3 = *(const float4*)(prow+36);
        v8h a0 = cvt8(f0,f1), a1 = cvt8(f2,f3);
        #pragma unroll
        for (int nt=0;nt<4;++nt){
            v4f acc = {};
            acc = MFMA32(a0, bb[nt][0], acc);
            acc = MFMA32(a1, bb[nt][1], acc);
            // acc: row = s-local = lq*4+i, col = bh = nt*16+l15
            int bh = nt*16 + l15;
            int bI = bh>>3;
            int4 mv = *(const int4*)(mask + ((size_t)(bI*Tt + t))*Tt + s0 + lq*4);
            v4h o;
            o[0] = mv.x ? (_Float16)acc[0] : (_Float16)(-30000.f);
            o[1] = mv.y ? (_Float16)acc[1] : (_Float16)(-30000.f);
            o[2] = mv.z ? (_Float16)acc[2] : (_Float16)(-30000.f);
            o[3] = mv.w ? (_Float16)acc[3] : (_Float16)(-30000.f);
            *(v4h*)(Sb + ((size_t)bh<<20) + ((size_t)t<<10) + s0 + lq*4) = o;
        }
    }
}

// ---------------- flash: content QK + bias + online softmax + PV -------------
// grid (64 bh, 8 t-tiles of 128), 256 thr (4 waves, each owns 32 t-rows)
__global__ __launch_bounds__(256) void k_flash(const _Float16* __restrict__ qs,
                                               const _Float16* __restrict__ kbuf,
                                               const _Float16* __restrict__ vbuf,
                                               const _Float16* __restrict__ Sb,
                                               _Float16* __restrict__ ao){
    __shared__ _Float16 Kl[64*64];   // [s][d] swizzled
    __shared__ _Float16 Vt[64*64];   // [d][s] swizzled
    __shared__ _Float16 Bl[128*64];  // bias chunk then P, [t][s] swizzled
    int bh = blockIdx.x; int b = bh>>3, h = bh&7;
    int t0 = blockIdx.y*128;
    int tid = threadIdx.x, l = tid&63, w = tid>>6, l15 = l&15, lq = l>>4;

    // resident Q A-frags (scaled fp16)
    v8h qa[2][2];
    #pragma unroll
    for (int mt=0;mt<2;++mt){
        #pragma unroll
        for (int u=0;u<2;++u)
            qa[mt][u] = *(const v8h*)(qs + ((size_t)(b*Tt + t0 + w*32 + mt*16 + l15))*NFf + h*DKk + u*32 + lq*8);
    }
    v4f O[2][4] = {};
    float mrow[2][4], lrow[2][4];
    #pragma unroll
    for (int mt=0;mt<2;++mt){
        #pragma unroll
        for (int i=0;i<4;i++){ mrow[mt][i] = -1e30f; lrow[mt][i] = 0.f; }
    }

    for (int sc=0; sc<16; ++sc){
        int s0 = sc*64;
        {   // stage K chunk [64 s][64 d]
            int r = tid>>2, seg = tid&3;
            const v8h* src = (const v8h*)(kbuf + ((size_t)(b*Tt + s0 + r))*NFf + h*DKk + seg*16);
            v8h k0 = src[0], k1 = src[1];
            *(v8h*)&Kl[swz(r, seg*16)]   = k0;
            *(v8h*)&Kl[swz(r, seg*16+8)] = k1;
        }
        {   // stage V transposed -> Vt[d][s]
            int s = tid&63;
            #pragma unroll
            for (int half=0; half<2; ++half){
                int d0 = (tid>>6)*8 + half*32;
                v8h vv = *(const v8h*)(vbuf + ((size_t)(b*Tt + s0 + s))*NFf + h*DKk + d0);
                #pragma unroll
                for (int j=0;j<8;j++) Vt[swz(d0+j, s)] = vv[j];
            }
        }
        {   // stage bias chunk [128 t][64 s] -- FULL 64 cols (round-3 bug fix)
            int r = tid>>1, hf = tid&1;
            const v8h* src = (const v8h*)(Sb + ((size_t)bh<<20) + ((size_t)(t0+r)<<10) + s0 + hf*32);
            v8h b0 = src[0], b1 = src[1], b2 = src[2], b3 = src[3];
            *(v8h*)&Bl[swz(r, hf*32)]    = b0;
            *(v8h*)&Bl[swz(r, hf*32+8)]  = b1;
            *(v8h*)&Bl[swz(r, hf*32+16)] = b2;
            *(v8h*)&Bl[swz(r, hf*32+24)] = b3;
        }
        __syncthreads();

        #pragma unroll
        for (int mt=0; mt<2; ++mt){
            v4f sv[4];
            #pragma unroll
            for (int nt=0; nt<4; ++nt){
                v8h kb0 = *(v8h*)&Kl[swz(nt*16+l15, lq*8)];
                v8h kb1 = *(v8h*)&Kl[swz(nt*16+l15, 32+lq*8)];
                v4f a = {};
                a = MFMA32(qa[mt][0], kb0, a);
                a = MFMA32(qa[mt][1], kb1, a);
                int rb = w*32 + mt*16;
                #pragma unroll
                for (int i=0;i<4;i++)
                    a[i] += (float)Bl[swz(rb + lq*4 + i, nt*16 + l15)];
                sv[nt] = a;
            }
            #pragma unroll
            for (int i=0;i<4;i++){
                float mx = fmaxf(fmaxf(sv[0][i],sv[1][i]),fmaxf(sv[2][i],sv[3][i]));
                mx = fmaxf(mx, __shfl_xor(mx,1));
                mx = fmaxf(mx, __shfl_xor(mx,2));
                mx = fmaxf(mx, __shfl_xor(mx,4));
                mx = fmaxf(mx, __shfl_xor(mx,8));
                float mo = mrow[mt][i];
                float mn = fmaxf(mo, mx);
                float rsc = exp2f(mo - mn);
                mrow[mt][i] = mn;
                lrow[mt][i] *= rsc;
                #pragma unroll
                for (int nt=0; nt<4; ++nt) O[mt][nt][i] *= rsc;
                float ps = 0.f;
                #pragma unroll
                for (int nt=0; nt<4; ++nt){
                    float pv = exp2f(sv[nt][i] - mn);
                    sv[nt][i] = pv;
                    ps += pv;
                }
                ps += __shfl_xor(ps,1);
                ps += __shfl_xor(ps,2);
                ps += __shfl_xor(ps,4);
                ps += __shfl_xor(ps,8);
                lrow[mt][i] += ps;
            }
            // write P (fp16) into Bl over this wave's rows
            #pragma unroll
            for (int nt=0;nt<4;++nt){
                #pragma unroll
                for (int i=0;i<4;i++)
                    Bl[swz(w*32+mt*16+lq*4+i, nt*16+l15)] = (_Float16)sv[nt][i];
            }
        }
        // PV: A = P rows (own wave), B = Vt
        #pragma unroll
        for (int mt=0; mt<2; ++mt){
            v8h pa0 = *(v8h*)&Bl[swz(w*32+mt*16+l15, lq*8)];
            v8h pa1 = *(v8h*)&Bl[swz(w*32+mt*16+l15, 32+lq*8)];
            #pragma unroll
            for (int nt=0; nt<4; ++nt){
                v8h vb0 = *(v8h*)&Vt[swz(nt*16+l15, lq*8)];
                v8h vb1 = *(v8h*)&Vt[swz(nt*16+l15, 32+lq*8)];
                O[mt][nt] = MFMA32(pa0, vb0, O[mt][nt]);
                O[mt][nt] = MFMA32(pa1, vb1, O[mt][nt]);
            }
        }
        __syncthreads();
    }

    #pragma unroll
    for (int mt=0; mt<2; ++mt){
        #pragma unroll
        for (int i=0;i<4;i++){
            float lr = lrow[mt][i];
            float rl = (lr > 0.f) ? 1.f/lr : 0.f;
            int row = t0 + w*32 + mt*16 + lq*4 + i;
            #pragma unroll
            for (int nt=0; nt<4; ++nt)
                ao[((size_t)(b*Tt + row))*NFf + h*DKk + nt*16 + l15] = (_Float16)(O[mt][nt][i]*rl);
        }
    }
}

// ---------------- launch ----------------
extern "C" void kernel_launch(void* const* d_in, const int* in_sizes, int n_in,
                              void* d_out, int out_size, void* d_ws, size_t ws_size,
                              hipStream_t stream) {
    const float* x       = (const float*)d_in[0];
    const float* cond    = (const float*)d_in[1];
    const float* pos_k   = (const float*)d_in[2];
    const int*   mask    = (const int*)  d_in[3];
    const float* ln_g    = (const float*)d_in[4];
    const float* ln_b    = (const float*)d_in[5];
    const float* Wq      = (const float*)d_in[6];
    const float* bq      = (const float*)d_in[7];
    const float* Wk      = (const float*)d_in[8];
    const float* bk      = (const float*)d_in[9];
    const float* Wv      = (const float*)d_in[10];
    const float* bv      = (const float*)d_in[11];
    const float* Wo      = (const float*)d_in[12];
    const float* bo      = (const float*)d_in[13];
    const float* Wc      = (const float*)d_in[14];
    const float* bc      = (const float*)d_in[15];
    float* out = (float*)d_out;

    char* base = (char*)d_ws;
    const size_t OFF_S   = 0;                       // 134217728 B fp16 bias/Sb
    const size_t OFF_XN  = 134217728;
    const size_t OFF_Q   = OFF_XN  + 8388608;
    const size_t OFF_QB  = OFF_Q   + 8388608;
    const size_t OFF_K   = OFF_QB  + 8388608;
    const size_t OFF_V   = OFF_K   + 8388608;
    const size_t OFF_AO  = OFF_V   + 8388608;
    const size_t OFF_WCQ = OFF_AO  + 8388608;
    const size_t OFF_BCQ = OFF_WCQ + 524288;

    _Float16* xn   = (_Float16*)(base + OFF_XN);
    _Float16* qbuf = (_Float16*)(base + OFF_Q);
    _Float16* qb   = (_Float16*)(base + OFF_QB);
    _Float16* kb   = (_Float16*)(base + OFF_K);
    _Float16* vb   = (_Float16*)(base + OFF_V);
    _Float16* ao   = (_Float16*)(base + OFF_AO);
    _Float16* Sb   = (_Float16*)(base + OFF_S);
    float*    wcq  = (float*)(base + OFF_WCQ);
    float*    bcq  = (float*)(base + OFF_BCQ);

    k_ln<<<dim3(Bb*Tt), dim3(256), 0, stream>>>(x, ln_g, ln_b, xn);
    k_wcq<<<dim3(32), dim3(512), 0, stream>>>(Wc, Wq, wcq);
    k_bcq<<<dim3(1), dim3(512), 0, stream>>>(bc, Wq, bq, bcq);

    // q projection: writes scaled qbuf AND scaled transposed qb
    k_gemm<float,_Float16,true><<<dim3(8,128), dim3(256), 0, stream>>>(cond, wcq, bcq, qbuf, Bb*Tt, 512, 256, SCQ, qb);
    k_gemm<_Float16,_Float16,false><<<dim3(8,128), dim3(256), 0, stream>>>(xn, Wk, bk, kb, Bb*Tt, 512, 512, 1.f, nullptr);
    k_gemm<_Float16,_Float16,false><<<dim3(8,128), dim3(256), 0, stream>>>(xn, Wv, bv, vb, Bb*Tt, 512, 512, 1.f, nullptr);

    k_bias<<<dim3(1024), dim3(256), 0, stream>>>(qb, pos_k, mask, Sb);
    k_flash<<<dim3(64,8), dim3(256), 0, stream>>>(qbuf, kb, vb, Sb, ao);

    k_gemm<_Float16,float,false><<<dim3(8,128), dim3(256), 0, stream>>>(ao, Wo, bo, out, Bb*Tt, 512, 512, 1.f, nullptr);
}

// Round 5
// 407.147 us; speedup vs baseline: 1.7008x; 1.1051x over previous
//
#include <hip/hip_runtime.h>

// ---------------- problem constants ----------------
#define Bb 8
#define Tt 1024
#define Hh 8
#define DKk 64
#define NFf 512
#define DCc 256

typedef _Float16 v2h __attribute__((ext_vector_type(2)));
typedef _Float16 v4h __attribute__((ext_vector_type(4)));
typedef _Float16 v8h __attribute__((ext_vector_type(8)));
typedef float    v4f __attribute__((ext_vector_type(4)));

#define MFMA16(a,b,c) __builtin_amdgcn_mfma_f32_16x16x16f16((a),(b),(c),0,0,0)
#define MFMA32(a,b,c) __builtin_amdgcn_mfma_f32_16x16x32_f16((a),(b),(c),0,0,0)

// scale folded into q: 1/sqrt(64) * log2(e)  (scores live in log2 domain)
#define SCQ 0.1803368801111f

__device__ inline void st8(_Float16* dst, v8h x){
    *(v4h*)dst     = __builtin_shufflevector(x,x,0,1,2,3);
    *(v4h*)(dst+4) = __builtin_shufflevector(x,x,4,5,6,7);
}

__device__ inline v8h cvt8(float4 a, float4 b){
    v8h r;
    r[0]=(_Float16)a.x; r[1]=(_Float16)a.y; r[2]=(_Float16)a.z; r[3]=(_Float16)a.w;
    r[4]=(_Float16)b.x; r[5]=(_Float16)b.y; r[6]=(_Float16)b.z; r[7]=(_Float16)b.w;
    return r;
}

// XOR swizzle for [R][64] half LDS tiles; keeps 8-half granularity
__device__ inline int swz(int r, int c){ return (r*64 + c) ^ ((r&7)<<3); }

// ---------------- LayerNorm: x (8192,512) fp32 -> xn fp16 ----------------
__global__ __launch_bounds__(256) void k_ln(const float* __restrict__ x,
                                            const float* __restrict__ g,
                                            const float* __restrict__ be,
                                            _Float16* __restrict__ xn){
    int row = blockIdx.x; int tid = threadIdx.x;
    const float* xr = x + (size_t)row*512;
    float2 v = reinterpret_cast<const float2*>(xr)[tid];
    float s = v.x + v.y, sq = v.x*v.x + v.y*v.y;
    for (int off=32; off; off>>=1){ s += __shfl_down(s, off); sq += __shfl_down(sq, off); }
    __shared__ float ws_[4], wq_[4];
    __shared__ float mu_s, rs_s;
    int wid = tid>>6, lid = tid&63;
    if (lid==0){ ws_[wid]=s; wq_[wid]=sq; }
    __syncthreads();
    if (tid==0){
        float S=0,Q=0;
        for(int i=0;i<4;i++){S+=ws_[i];Q+=wq_[i];}
        float mu = S*(1.f/512.f);
        float var = Q*(1.f/512.f)-mu*mu;
        mu_s=mu; rs_s=rsqrtf(var+1e-5f);
    }
    __syncthreads();
    float mu=mu_s, rs=rs_s;
    float2 gv = reinterpret_cast<const float2*>(g)[tid];
    float2 bv = reinterpret_cast<const float2*>(be)[tid];
    v2h o; o[0] = (_Float16)((v.x-mu)*rs*gv.x + bv.x);
           o[1] = (_Float16)((v.y-mu)*rs*gv.y + bv.y);
    reinterpret_cast<v2h*>(xn + (size_t)row*512)[tid] = o;
}

// ---------------- Wcq = Wc(256,512) @ Wq(512,512), fp32 out ----------------
__global__ __launch_bounds__(512) void k_wcq(const float* __restrict__ Wc,
                                             const float* __restrict__ Wq,
                                             float* __restrict__ Wcq){
    __shared__ float wc[8][512];
    int i0 = blockIdx.x*8; int tid = threadIdx.x;
    for (int r=0;r<8;r++) wc[r][tid] = Wc[(size_t)(i0+r)*512 + tid];
    __syncthreads();
    float acc[8] = {0,0,0,0,0,0,0,0};
    for (int m=0;m<512;m++){
        float wq = Wq[(size_t)m*512+tid];
        #pragma unroll
        for (int r=0;r<8;r++) acc[r] += wc[r][m]*wq;
    }
    for (int r=0;r<8;r++) Wcq[(size_t)(i0+r)*512+tid] = acc[r];
}

// ---------------- bcq = bc @ Wq + bq ----------------
__global__ __launch_bounds__(512) void k_bcq(const float* __restrict__ bc,
                                             const float* __restrict__ Wq,
                                             const float* __restrict__ bq,
                                             float* __restrict__ bcq){
    int j = threadIdx.x;
    float a = bq[j];
    for (int m=0;m<512;m++) a += bc[m]*Wq[(size_t)m*512+j];
    bcq[j] = a;
}

// ---------------- generic GEMM: C(M,N) = (A(M,K) @ W(K,N) + bias)*scale -------
// QB: additionally write q-transposed layout qbT[t][b*512+c]
template<typename AT, typename CT, bool QB>
__global__ __launch_bounds__(256) void k_gemm(const AT* __restrict__ A,
                                              const float* __restrict__ W,
                                              const float* __restrict__ bias,
                                              CT* __restrict__ C,
                                              int M, int N, int K,
                                              float scale,
                                              _Float16* __restrict__ qbT){
    __shared__ _Float16 Al[64][36];
    __shared__ _Float16 Wt[64][36];
    int tid = threadIdx.x; int l = tid & 63; int w = tid >> 6;
    int l15 = l & 15, lq = l >> 4;
    int m0 = blockIdx.y*64, n0 = blockIdx.x*64;
    v4f acc[4] = {};
    float bv[4];
    #pragma unroll
    for (int nt=0;nt<4;nt++) bv[nt] = bias[n0 + nt*16 + l15];
    int arow = tid>>2, aseg = (tid&3)*8;
    int wk = tid>>3,  wn  = (tid&7)*8;
    for (int k0=0;k0<K;k0+=32){
        if constexpr (sizeof(AT)==4){
            const float* src = (const float*)A + (size_t)(m0+arow)*K + k0 + aseg;
            float4 f0 = *(const float4*)src;
            float4 f1 = *(const float4*)(src+4);
            *(v4h*)&Al[arow][aseg]   = (v4h){(_Float16)f0.x,(_Float16)f0.y,(_Float16)f0.z,(_Float16)f0.w};
            *(v4h*)&Al[arow][aseg+4] = (v4h){(_Float16)f1.x,(_Float16)f1.y,(_Float16)f1.z,(_Float16)f1.w};
        } else {
            const _Float16* src = (const _Float16*)A + (size_t)(m0+arow)*K + k0 + aseg;
            v8h hv = *(const v8h*)src;
            st8(&Al[arow][aseg], hv);
        }
        {
            const float* src = W + (size_t)(k0+wk)*N + n0 + wn;
            float4 f0 = *(const float4*)src;
            float4 f1 = *(const float4*)(src+4);
            float tmp[8] = {f0.x,f0.y,f0.z,f0.w,f1.x,f1.y,f1.z,f1.w};
            #pragma unroll
            for (int j=0;j<8;j++) Wt[wn+j][wk] = (_Float16)tmp[j];
        }
        __syncthreads();
        #pragma unroll
        for (int kk=0; kk<32; kk+=16){
            v4h a = *(const v4h*)&Al[w*16 + l15][kk + lq*4];
            #pragma unroll
            for (int nt=0;nt<4;nt++){
                v4h b = *(const v4h*)&Wt[nt*16 + l15][kk + lq*4];
                acc[nt] = MFMA16(a, b, acc[nt]);
            }
        }
        __syncthreads();
    }
    #pragma unroll
    for (int nt=0;nt<4;nt++){
        #pragma unroll
        for (int i=0;i<4;i++){
            int row = m0 + w*16 + lq*4 + i;
            int col = n0 + nt*16 + l15;
            float vfull = (acc[nt][i] + bv[nt])*scale;
            C[(size_t)row*N + col] = (CT)vfull;
            if constexpr (QB){
                int bI = row>>10, t = row&1023;
                qbT[((size_t)t<<12) + (bI<<9) + col] = (_Float16)vfull;
            }
        }
    }
}

// ---------------- bias v2: Sb[bh][t][s] = qb[t,bh,:]·posk[t,s,:], mask folded -
// grid 2048 (t = blk>>1, s-half = blk&1), 256 thr; wave w owns 128 s values.
// MFMA roles: A = qb (rows = bh), B = posk (cols = s) -> stores coalesced in s.
__global__ __launch_bounds__(256) void k_bias(const _Float16* __restrict__ qb,
                                              const float* __restrict__ posk,
                                              const int* __restrict__ mask,
                                              _Float16* __restrict__ Sb){
    int t = blockIdx.x >> 1, sh = blockIdx.x & 1;
    int tid = threadIdx.x, l = tid&63, w = tid>>6, l15 = l&15, lq = l>>4;
    // resident A-frags: A[row=bh][k=d] = qb[t][bh*64+d]
    v8h aa[4][2];
    const _Float16* qbt = qb + ((size_t)t<<12);
    #pragma unroll
    for (int nt=0;nt<4;++nt){
        #pragma unroll
        for (int u=0;u<2;++u)
            aa[nt][u] = *(const v8h*)(qbt + (nt*16+l15)*64 + u*32 + lq*8);
    }
    const float* pkt = posk + ((size_t)t<<16);
    int sbase = sh*512 + w*128;
    #pragma unroll 2
    for (int st=0; st<8; ++st){
        int s0 = sbase + st*16;
        const float* prow = pkt + (size_t)(s0 + l15)*64 + lq*8;
        float4 f0 = *(const float4*)(prow);
        float4 f1 = *(const float4*)(prow+4);
        float4 f2 = *(const float4*)(prow+32);
        float4 f3 = *(const float4*)(prow+36);
        v8h b0 = cvt8(f0,f1), b1 = cvt8(f2,f3);
        #pragma unroll
        for (int nt=0;nt<4;++nt){
            v4f acc = {};
            acc = MFMA32(aa[nt][0], b0, acc);
            acc = MFMA32(aa[nt][1], b1, acc);
            // row = bh = nt*16 + lq*4 + i, col = s = s0 + l15
            // b = bh>>3 = 2nt + (lq>>1)  (independent of i)
            int m = mask[(((size_t)((2*nt + (lq>>1))*Tt + t))<<10) + s0 + l15];
            _Float16 res[4];
            #pragma unroll
            for (int i=0;i<4;i++)
                res[i] = m ? (_Float16)acc[i] : (_Float16)(-30000.f);
            #pragma unroll
            for (int i=0;i<4;i++){
                int bh = nt*16 + lq*4 + i;
                Sb[((size_t)bh<<20) + ((size_t)t<<10) + s0 + l15] = res[i];
            }
        }
    }
}

// ---------------- flash: content QK + bias + online softmax + PV -------------
// grid (64 bh, 16 t-tiles of 64), 256 thr (4 waves, each owns 16 t-rows)
__global__ __launch_bounds__(256) void k_flash(const _Float16* __restrict__ qs,
                                               const _Float16* __restrict__ kbuf,
                                               const _Float16* __restrict__ vbuf,
                                               const _Float16* __restrict__ Sb,
                                               _Float16* __restrict__ ao){
    __shared__ _Float16 Kl[64*64];   // [s][d] swizzled
    __shared__ _Float16 Vt[64*64];   // [d][s] swizzled
    __shared__ _Float16 Bl[64*64];   // bias chunk then P, [t][s] swizzled
    int bh = blockIdx.x; int b = bh>>3, h = bh&7;
    int t0 = blockIdx.y*64;
    int tid = threadIdx.x, l = tid&63, w = tid>>6, l15 = l&15, lq = l>>4;

    // resident Q A-frags (scaled fp16), rows t0 + w*16 + l15
    v8h qa[2];
    #pragma unroll
    for (int u=0;u<2;++u)
        qa[u] = *(const v8h*)(qs + ((size_t)(b*Tt + t0 + w*16 + l15))*NFf + h*DKk + u*32 + lq*8);

    v4f O[4] = {};
    float mrow[4], lrow[4];
    #pragma unroll
    for (int i=0;i<4;i++){ mrow[i] = -1e30f; lrow[i] = 0.f; }

    for (int sc=0; sc<16; ++sc){
        int s0 = sc*64;
        {   // stage K chunk [64 s][64 d]
            int r = tid>>2, seg = tid&3;
            const v8h* src = (const v8h*)(kbuf + ((size_t)(b*Tt + s0 + r))*NFf + h*DKk + seg*16);
            v8h k0 = src[0], k1 = src[1];
            *(v8h*)&Kl[swz(r, seg*16)]   = k0;
            *(v8h*)&Kl[swz(r, seg*16+8)] = k1;
        }
        {   // stage V transposed -> Vt[d][s]
            int s = tid&63;
            #pragma unroll
            for (int half=0; half<2; ++half){
                int d0 = (tid>>6)*8 + half*32;
                v8h vv = *(const v8h*)(vbuf + ((size_t)(b*Tt + s0 + s))*NFf + h*DKk + d0);
                #pragma unroll
                for (int j=0;j<8;j++) Vt[swz(d0+j, s)] = vv[j];
            }
        }
        {   // stage bias chunk [64 t][64 s]
            int r = tid>>2, hf = tid&3;
            const v8h* src = (const v8h*)(Sb + ((size_t)bh<<20) + ((size_t)(t0+r)<<10) + s0 + hf*16);
            v8h b0 = src[0], b1 = src[1];
            *(v8h*)&Bl[swz(r, hf*16)]   = b0;
            *(v8h*)&Bl[swz(r, hf*16+8)] = b1;
        }
        __syncthreads();

        v4f sv[4];
        #pragma unroll
        for (int nt=0; nt<4; ++nt){
            v8h kb0 = *(v8h*)&Kl[swz(nt*16+l15, lq*8)];
            v8h kb1 = *(v8h*)&Kl[swz(nt*16+l15, 32+lq*8)];
            v4f a = {};
            a = MFMA32(qa[0], kb0, a);
            a = MFMA32(qa[1], kb1, a);
            int rb = w*16;
            #pragma unroll
            for (int i=0;i<4;i++)
                a[i] += (float)Bl[swz(rb + lq*4 + i, nt*16 + l15)];
            sv[nt] = a;
        }
        #pragma unroll
        for (int i=0;i<4;i++){
            float mx = fmaxf(fmaxf(sv[0][i],sv[1][i]),fmaxf(sv[2][i],sv[3][i]));
            mx = fmaxf(mx, __shfl_xor(mx,1));
            mx = fmaxf(mx, __shfl_xor(mx,2));
            mx = fmaxf(mx, __shfl_xor(mx,4));
            mx = fmaxf(mx, __shfl_xor(mx,8));
            float mo = mrow[i];
            float mn = fmaxf(mo, mx);
            float rsc = exp2f(mo - mn);
            mrow[i] = mn;
            lrow[i] *= rsc;
            #pragma unroll
            for (int nt=0; nt<4; ++nt) O[nt][i] *= rsc;
            float ps = 0.f;
            #pragma unroll
            for (int nt=0; nt<4; ++nt){
                float pv = exp2f(sv[nt][i] - mn);
                sv[nt][i] = pv;
                ps += pv;
            }
            ps += __shfl_xor(ps,1);
            ps += __shfl_xor(ps,2);
            ps += __shfl_xor(ps,4);
            ps += __shfl_xor(ps,8);
            lrow[i] += ps;
        }
        // write P (fp16) into Bl over this wave's rows
        #pragma unroll
        for (int nt=0;nt<4;++nt){
            #pragma unroll
            for (int i=0;i<4;i++)
                Bl[swz(w*16+lq*4+i, nt*16+l15)] = (_Float16)sv[nt][i];
        }
        // PV: A = P rows (own wave), B = Vt
        {
            v8h pa0 = *(v8h*)&Bl[swz(w*16+l15, lq*8)];
            v8h pa1 = *(v8h*)&Bl[swz(w*16+l15, 32+lq*8)];
            #pragma unroll
            for (int nt=0; nt<4; ++nt){
                v8h vb0 = *(v8h*)&Vt[swz(nt*16+l15, lq*8)];
                v8h vb1 = *(v8h*)&Vt[swz(nt*16+l15, 32+lq*8)];
                O[nt] = MFMA32(pa0, vb0, O[nt]);
                O[nt] = MFMA32(pa1, vb1, O[nt]);
            }
        }
        __syncthreads();
    }

    #pragma unroll
    for (int i=0;i<4;i++){
        float lr = lrow[i];
        float rl = (lr > 0.f) ? 1.f/lr : 0.f;
        int row = t0 + w*16 + lq*4 + i;
        #pragma unroll
        for (int nt=0; nt<4; ++nt)
            ao[((size_t)(b*Tt + row))*NFf + h*DKk + nt*16 + l15] = (_Float16)(O[nt][i]*rl);
    }
}

// ---------------- launch ----------------
extern "C" void kernel_launch(void* const* d_in, const int* in_sizes, int n_in,
                              void* d_out, int out_size, void* d_ws, size_t ws_size,
                              hipStream_t stream) {
    const float* x       = (const float*)d_in[0];
    const float* cond    = (const float*)d_in[1];
    const float* pos_k   = (const float*)d_in[2];
    const int*   mask    = (const int*)  d_in[3];
    const float* ln_g    = (const float*)d_in[4];
    const float* ln_b    = (const float*)d_in[5];
    const float* Wq      = (const float*)d_in[6];
    const float* bq      = (const float*)d_in[7];
    const float* Wk      = (const float*)d_in[8];
    const float* bk      = (const float*)d_in[9];
    const float* Wv      = (const float*)d_in[10];
    const float* bv      = (const float*)d_in[11];
    const float* Wo      = (const float*)d_in[12];
    const float* bo      = (const float*)d_in[13];
    const float* Wc      = (const float*)d_in[14];
    const float* bc      = (const float*)d_in[15];
    float* out = (float*)d_out;

    char* base = (char*)d_ws;
    const size_t OFF_S   = 0;                       // 134217728 B fp16 bias/Sb
    const size_t OFF_XN  = 134217728;
    const size_t OFF_Q   = OFF_XN  + 8388608;
    const size_t OFF_QB  = OFF_Q   + 8388608;
    const size_t OFF_K   = OFF_QB  + 8388608;
    const size_t OFF_V   = OFF_K   + 8388608;
    const size_t OFF_AO  = OFF_V   + 8388608;
    const size_t OFF_WCQ = OFF_AO  + 8388608;
    const size_t OFF_BCQ = OFF_WCQ + 524288;

    _Float16* xn   = (_Float16*)(base + OFF_XN);
    _Float16* qbuf = (_Float16*)(base + OFF_Q);
    _Float16* qb   = (_Float16*)(base + OFF_QB);
    _Float16* kb   = (_Float16*)(base + OFF_K);
    _Float16* vb   = (_Float16*)(base + OFF_V);
    _Float16* ao   = (_Float16*)(base + OFF_AO);
    _Float16* Sb   = (_Float16*)(base + OFF_S);
    float*    wcq  = (float*)(base + OFF_WCQ);
    float*    bcq  = (float*)(base + OFF_BCQ);

    k_ln<<<dim3(Bb*Tt), dim3(256), 0, stream>>>(x, ln_g, ln_b, xn);
    k_wcq<<<dim3(32), dim3(512), 0, stream>>>(Wc, Wq, wcq);
    k_bcq<<<dim3(1), dim3(512), 0, stream>>>(bc, Wq, bq, bcq);

    // q projection: writes scaled qbuf AND scaled transposed qb
    k_gemm<float,_Float16,true><<<dim3(8,128), dim3(256), 0, stream>>>(cond, wcq, bcq, qbuf, Bb*Tt, 512, 256, SCQ, qb);
    k_gemm<_Float16,_Float16,false><<<dim3(8,128), dim3(256), 0, stream>>>(xn, Wk, bk, kb, Bb*Tt, 512, 512, 1.f, nullptr);
    k_gemm<_Float16,_Float16,false><<<dim3(8,128), dim3(256), 0, stream>>>(xn, Wv, bv, vb, Bb*Tt, 512, 512, 1.f, nullptr);

    k_bias<<<dim3(2048), dim3(256), 0, stream>>>(qb, pos_k, mask, Sb);
    k_flash<<<dim3(64,16), dim3(256), 0, stream>>>(qbuf, kb, vb, Sb, ao);

    k_gemm<_Float16,float,false><<<dim3(8,128), dim3(256), 0, stream>>>(ao, Wo, bo, out, Bb*Tt, 512, 512, 1.f, nullptr);
}